// Round 5
// baseline (369.717 us; speedup 1.0000x reference)
//
#include <hip/hip_runtime.h>
#include <math.h>

// x_in: (32768, 543, 3) fp32; out = [5 stat feats of 480] + [16384*240] = 3934560 fp32
// Bilinear 2:1 resize (half-pixel, antialias=False) == out[i] = 0.5*(x[2i]+x[2i+1]).
// 32768 % 4 == 0 -> no symmetric padding; segments are exactly 4 x 8192 frames.
#define T_FRAMES   32768
#define FRAME      1629              // 543*3 floats per frame
#define FPB        16                // frames per block
#define NBLOCKS    (T_FRAMES / FPB)  // 2048 blocks (8/CU nominal, 6/CU LDS-capped)
#define OUT_B_OFF  2400              // 5 feats * 480
#define SEG_BLOCKS (NBLOCKS / 4)     // 512 blocks per segment
#define MID_OFF    ((size_t)NBLOCKS * 480)  // float offset of mid[16][480] in ws

__constant__ int c_astart[10] = {0, 40, 80, 140, 200, 260, 320, 370, 420, 480};
__constant__ int c_alen[10]   = {40, 40, 60, 60, 60, 60, 50, 50, 60, 63};

// One block = 16 consecutive frames = 8 output rows. Stage unit = 4 frames
// (1629 float4, 16B/lane coalesced) -> 26 KB LDS. Register-prefetch pipeline:
// unit u+1's global loads are issued before compute on unit u, overlapping
// HBM fetch with VALU work inside each block (ILP), on top of 6-blocks/CU TLP.
__global__ __launch_bounds__(256) void featgen_main(
    const float* __restrict__ xin, float* __restrict__ out, float* __restrict__ part)
{
    __shared__ float rows[4 * FRAME];   // 26064 B
    __shared__ float xavg[4 * 32];      // 4 frames x 30 range-means (padded)

    const int t = threadIdx.x;
    const int b = blockIdx.x;
    const float* src = xin + (size_t)b * (FPB * FRAME);

    // Phase-A role: 8 lanes per (landmark-range, channel); groups stay in-wave.
    const int g8 = t >> 3;   // 0..31, active if < 30
    const int j8 = t & 7;
    int a_s = 0, a_n = 0, a_c = 0;
    float a_inv = 0.0f;
    if (g8 < 30) {
        int l = g8 / 3; a_c = g8 - 3 * l;
        a_s = c_astart[l]; a_n = c_alen[l];
        a_inv = 1.0f / (float)a_n;
    }

    float ssum = 0.0f, ssq = 0.0f;   // thread t owns feature k=t (t<240)

    // Prefetch unit 0 into registers.
    float4 pf[7];
    {
        const float4* s4 = (const float4*)src;
        #pragma unroll
        for (int i = 0; i < 7; ++i) {
            int idx = t + i * 256;
            if (idx < FRAME) pf[i] = s4[idx];
        }
    }

    for (int u = 0; u < 4; ++u) {
        if (u > 0) __syncthreads();          // prior unit's readers done
        // ---- drain prefetch regs into LDS ----
        float4* d4 = (float4*)rows;
        #pragma unroll
        for (int i = 0; i < 7; ++i) {
            int idx = t + i * 256;
            if (idx < FRAME) d4[idx] = pf[i];
        }
        __syncthreads();

        // ---- issue next unit's global loads (overlap with compute below) ----
        if (u < 3) {
            const float4* s4 = (const float4*)(src + (u + 1) * (4 * FRAME));
            #pragma unroll
            for (int i = 0; i < 7; ++i) {
                int idx = t + i * 256;
                if (idx < FRAME) pf[i] = s4[idx];
            }
        }

        // ---- phase A: cooperative range-means (8 lanes each, shfl reduce) ----
        if (g8 < 30) {
            #pragma unroll
            for (int f = 0; f < 4; ++f) {
                const float* row = rows + f * FRAME;
                float s = 0.0f;
                for (int j = j8; j < a_n; j += 8) s += row[(a_s + j) * 3 + a_c];
                s += __shfl_xor(s, 1, 8);
                s += __shfl_xor(s, 2, 8);
                s += __shfl_xor(s, 4, 8);
                if (j8 == 0) xavg[f * 32 + g8] = s * a_inv;
            }
        }
        __syncthreads();

        // ---- phase B: two pair-averaged output rows + stats accumulation ----
        if (t < 240) {
            float v0, v1, v2, v3;
            if (t < 30) {
                v0 = xavg[t];      v1 = xavg[32 + t];
                v2 = xavg[64 + t]; v3 = xavg[96 + t];
            } else {
                // point landmark 468+(l-10): frame offset = t + 468*3 - 30 = t+1374
                v0 = rows[t + 1374];
                v1 = rows[FRAME + t + 1374];
                v2 = rows[2 * FRAME + t + 1374];
                v3 = rows[3 * FRAME + t + 1374];
            }
            const size_t row0 = (size_t)b * 8 + (size_t)u * 2;
            out[OUT_B_OFF + row0 * 240 + t]       = 0.5f * (v0 + v1);
            out[OUT_B_OFF + (row0 + 1) * 240 + t] = 0.5f * (v2 + v3);
            ssum += v0 + v1 + v2 + v3;
            ssq  += v0 * v0 + v1 * v1 + v2 * v2 + v3 * v3;
        }
    }

    // Deterministic per-block partials (no atomics, no zero-init kernel).
    if (t < 240) {
        part[(size_t)b * 480 + t]       = ssum;
        part[(size_t)b * 480 + 240 + t] = ssq;
    }
}

// Level-1 reduce: 16 blocks = (seg f, chunk c); each sums 128 block-partials.
// Launched with 512 threads -> launch_bounds must be >= 512.
__global__ __launch_bounds__(512) void reduce_parts(
    const float* __restrict__ part, float* __restrict__ mid)
{
    const int f = blockIdx.x >> 2;
    const int c = blockIdx.x & 3;
    const int t = threadIdx.x;
    if (t >= 480) return;
    const int b0 = f * SEG_BLOCKS + c * (SEG_BLOCKS / 4);
    float s = 0.0f;
    #pragma unroll 4
    for (int b = 0; b < SEG_BLOCKS / 4; ++b)
        s += part[(size_t)(b0 + b) * 480 + t];
    mid[(size_t)blockIdx.x * 480 + t] = s;
}

// Level-2: 5 blocks -> mean/std. f<4 sums 4 chunks of its segment; f=4 sums all 16.
__global__ __launch_bounds__(256) void finalize_stats(
    const float* __restrict__ mid, float* __restrict__ out)
{
    const int f = blockIdx.x;
    const int t = threadIdx.x;
    if (t >= 240) return;
    float s = 0.0f, q = 0.0f, n;
    if (f < 4) {
        #pragma unroll
        for (int c = 0; c < 4; ++c) {
            s += mid[(size_t)(f * 4 + c) * 480 + t];
            q += mid[(size_t)(f * 4 + c) * 480 + 240 + t];
        }
        n = 8192.0f;
    } else {
        #pragma unroll
        for (int m = 0; m < 16; ++m) {
            s += mid[(size_t)m * 480 + t];
            q += mid[(size_t)m * 480 + 240 + t];
        }
        n = 32768.0f;
    }
    float mean = s / n;
    float var  = q / n - mean * mean;
    var = var < 0.0f ? 0.0f : var;
    out[f * 480 + t]       = mean;
    out[f * 480 + 240 + t] = sqrtf(var);
}

extern "C" void kernel_launch(void* const* d_in, const int* in_sizes, int n_in,
                              void* d_out, int out_size, void* d_ws, size_t ws_size,
                              hipStream_t stream) {
    (void)in_sizes; (void)n_in; (void)out_size; (void)ws_size;
    const float* xin = (const float*)d_in[0];
    float* out  = (float*)d_out;
    float* part = (float*)d_ws;
    float* mid  = part + MID_OFF;

    featgen_main<<<NBLOCKS, 256, 0, stream>>>(xin, out, part);
    reduce_parts<<<16, 512, 0, stream>>>(part, mid);
    finalize_stats<<<5, 256, 0, stream>>>(mid, out);
}

// Round 6
// 318.644 us; speedup vs baseline: 1.1603x; 1.1603x over previous
//
#include <hip/hip_runtime.h>
#include <math.h>

// x_in: (32768, 543, 3) fp32; out = [5 stat feats of 480] + [16384*240] = 3934560 fp32
// Bilinear 2:1 resize (half-pixel, antialias=False) == out[i] = 0.5*(x[2i]+x[2i+1]).
// 32768 % 4 == 0 -> no symmetric padding; segments are exactly 4 x 8192 frames.
#define T_FRAMES   32768
#define FRAME      1629              // 543*3 floats per frame
#define FPB        16                // frames per block
#define NBLOCKS    (T_FRAMES / FPB)  // 2048
#define OUT_B_OFF  2400              // 5 feats * 480
#define SEG_BLOCKS (NBLOCKS / 4)     // 512 blocks per segment
#define MID_OFF    ((size_t)NBLOCKS * 480)  // float offset of mid[16][480] in ws
#define UNIT_F4    1629              // one unit = 4 frames = 1629 float4

__constant__ int c_astart[10] = {0, 40, 80, 140, 200, 260, 320, 370, 420, 480};
__constant__ int c_alen[10]   = {40, 40, 60, 60, 60, 60, 50, 50, 60, 63};

// Async global->LDS DMA, 16 B per lane. LDS dest is wave-uniform base + lane*16;
// our layout is exactly lane-contiguous, so per-lane pointers are valid.
__device__ __forceinline__ void dma16(const float4* g, float4* l) {
    __builtin_amdgcn_global_load_lds(
        (const __attribute__((address_space(1))) void*)g,
        (__attribute__((address_space(3))) void*)l,
        16, 0, 0);
}

// Raw barriers: __syncthreads() emits s_waitcnt vmcnt(0) which would drain the
// in-flight prefetch DMA (the m97 barrier-drain trap). We wait only as much as
// correctness needs. vmcnt retires in order, so vmcnt(N) => all but the N
// newest VMEM ops are complete.
#define WAIT_VM7()  asm volatile("s_waitcnt vmcnt(7) lgkmcnt(0)" ::: "memory")
#define WAIT_VM6()  asm volatile("s_waitcnt vmcnt(6) lgkmcnt(0)" ::: "memory")
#define WAIT_VM0()  asm volatile("s_waitcnt vmcnt(0) lgkmcnt(0)" ::: "memory")
#define WAIT_LGKM() asm volatile("s_waitcnt lgkmcnt(0)" ::: "memory")
#define BARRIER()   asm volatile("s_barrier" ::: "memory")

// One block = 16 consecutive frames = 8 output rows. Unit = 4 frames staged by
// async DMA into a double-buffered 2x26 KB LDS region; unit u+1's DMA overlaps
// compute on unit u. 3 blocks/CU (LDS-capped); latency hidden by ~84 KB of DMA
// in flight per CU, not by wave count.
__global__ __launch_bounds__(256) void featgen_main(
    const float* __restrict__ xin, float* __restrict__ out, float* __restrict__ part)
{
    __shared__ float rows[2][4 * FRAME];   // 2 x 26064 B
    __shared__ float xavg[4 * 32];         // 4 frames x 30 range-means (padded)

    const int t    = threadIdx.x;
    const int w    = t >> 6;               // wave 0..3
    const int lane = t & 63;
    const int b    = blockIdx.x;
    const float4* src4 = (const float4*)(xin + (size_t)b * (FPB * FRAME));

    // Per-wave DMA issue for one unit. Waves 0,1 issue 7 ops; waves 2,3 issue 6
    // (tail group i=6 covers float4 indices 1536..1628 only).
    auto issue = [&](int buf, int u) {
        const float4* g = src4 + (size_t)u * UNIT_F4;
        float4* l = (float4*)rows[buf];
        #pragma unroll
        for (int i = 0; i < 7; ++i) {
            int idx = i * 256 + w * 64 + lane;
            if (idx < UNIT_F4) dma16(g + idx, l + idx);
        }
    };

    // Phase-A role: 8 lanes per (landmark-range, channel); groups stay in-wave.
    const int g8 = t >> 3;   // 0..31, active if < 30
    const int j8 = t & 7;
    int a_s = 0, a_n = 0, a_c = 0;
    float a_inv = 0.0f;
    if (g8 < 30) {
        int l = g8 / 3; a_c = g8 - 3 * l;
        a_s = c_astart[l]; a_n = c_alen[l];
        a_inv = 1.0f / (float)a_n;
    }

    float ssum = 0.0f, ssq = 0.0f;   // thread t owns feature k=t (t<240)

    issue(0, 0);   // prologue: unit 0 DMA in flight

    for (int u = 0; u < 4; ++u) {
        const int cur = u & 1;
        if (u < 3) issue(cur ^ 1, u + 1);   // prefetch next unit (stays in flight)

        // Wait for THIS unit's DMA only (prefetch + any older stores excluded /
        // safely over-waited via in-order retirement), then raw barrier.
        if (u < 3) { if (w < 2) WAIT_VM7(); else WAIT_VM6(); }
        else       { WAIT_VM0(); }
        BARRIER();

        const float* rbase = rows[cur];

        // ---- phase A: cooperative range-means (8 lanes each, shfl reduce) ----
        if (g8 < 30) {
            #pragma unroll
            for (int f = 0; f < 4; ++f) {
                const float* row = rbase + f * FRAME;
                float s = 0.0f;
                for (int j = j8; j < a_n; j += 8) s += row[(a_s + j) * 3 + a_c];
                s += __shfl_xor(s, 1, 8);
                s += __shfl_xor(s, 2, 8);
                s += __shfl_xor(s, 4, 8);
                if (j8 == 0) xavg[f * 32 + g8] = s * a_inv;
            }
        }
        WAIT_LGKM(); BARRIER();

        // ---- phase B: two pair-averaged output rows + stats accumulation ----
        if (t < 240) {
            float v0, v1, v2, v3;
            if (t < 30) {
                v0 = xavg[t];      v1 = xavg[32 + t];
                v2 = xavg[64 + t]; v3 = xavg[96 + t];
            } else {
                // point landmark 468+(l-10): frame offset = t + 468*3 - 30 = t+1374
                v0 = rbase[t + 1374];
                v1 = rbase[FRAME + t + 1374];
                v2 = rbase[2 * FRAME + t + 1374];
                v3 = rbase[3 * FRAME + t + 1374];
            }
            const size_t row0 = (size_t)b * 8 + (size_t)u * 2;
            out[OUT_B_OFF + row0 * 240 + t]       = 0.5f * (v0 + v1);
            out[OUT_B_OFF + (row0 + 1) * 240 + t] = 0.5f * (v2 + v3);
            ssum += v0 + v1 + v2 + v3;
            ssq  += v0 * v0 + v1 * v1 + v2 * v2 + v3 * v3;
        }
        // All waves done reading rbase + xavg before next iteration's DMA/phase-A
        // overwrite them.
        WAIT_LGKM(); BARRIER();
    }

    // Deterministic per-block partials (no atomics, no zero-init kernel).
    if (t < 240) {
        part[(size_t)b * 480 + t]       = ssum;
        part[(size_t)b * 480 + 240 + t] = ssq;
    }
}

// Level-1 reduce: 16 blocks = (seg f, chunk c); each sums 128 block-partials.
// Launched with 512 threads -> launch_bounds must be >= 512.
__global__ __launch_bounds__(512) void reduce_parts(
    const float* __restrict__ part, float* __restrict__ mid)
{
    const int f = blockIdx.x >> 2;
    const int c = blockIdx.x & 3;
    const int t = threadIdx.x;
    if (t >= 480) return;
    const int b0 = f * SEG_BLOCKS + c * (SEG_BLOCKS / 4);
    float s = 0.0f;
    #pragma unroll 4
    for (int b = 0; b < SEG_BLOCKS / 4; ++b)
        s += part[(size_t)(b0 + b) * 480 + t];
    mid[(size_t)blockIdx.x * 480 + t] = s;
}

// Level-2: 5 blocks -> mean/std. f<4 sums 4 chunks of its segment; f=4 sums all 16.
__global__ __launch_bounds__(256) void finalize_stats(
    const float* __restrict__ mid, float* __restrict__ out)
{
    const int f = blockIdx.x;
    const int t = threadIdx.x;
    if (t >= 240) return;
    float s = 0.0f, q = 0.0f, n;
    if (f < 4) {
        #pragma unroll
        for (int c = 0; c < 4; ++c) {
            s += mid[(size_t)(f * 4 + c) * 480 + t];
            q += mid[(size_t)(f * 4 + c) * 480 + 240 + t];
        }
        n = 8192.0f;
    } else {
        #pragma unroll
        for (int m = 0; m < 16; ++m) {
            s += mid[(size_t)m * 480 + t];
            q += mid[(size_t)m * 480 + 240 + t];
        }
        n = 32768.0f;
    }
    float mean = s / n;
    float var  = q / n - mean * mean;
    var = var < 0.0f ? 0.0f : var;
    out[f * 480 + t]       = mean;
    out[f * 480 + 240 + t] = sqrtf(var);
}

extern "C" void kernel_launch(void* const* d_in, const int* in_sizes, int n_in,
                              void* d_out, int out_size, void* d_ws, size_t ws_size,
                              hipStream_t stream) {
    (void)in_sizes; (void)n_in; (void)out_size; (void)ws_size;
    const float* xin = (const float*)d_in[0];
    float* out  = (float*)d_out;
    float* part = (float*)d_ws;
    float* mid  = part + MID_OFF;

    featgen_main<<<NBLOCKS, 256, 0, stream>>>(xin, out, part);
    reduce_parts<<<16, 512, 0, stream>>>(part, mid);
    finalize_stats<<<5, 256, 0, stream>>>(mid, out);
}